// Round 4
// baseline (519.770 us; speedup 1.0000x reference)
//
#include <hip/hip_runtime.h>
#include <cstdint>
#include <cstddef>

typedef __bf16 bf16;
typedef __attribute__((ext_vector_type(8))) __bf16 bf16x8;
typedef __attribute__((ext_vector_type(4))) float f32x4;
typedef __attribute__((ext_vector_type(4))) unsigned int u32x4;

#define QN 2048

// v_sin_f32 / v_cos_f32 take REVOLUTIONS: sin(2*pi*x). tc in (0,1), freq<=1.
#if __has_builtin(__builtin_amdgcn_sinf)
#define SIN_REV(x) __builtin_amdgcn_sinf(x)
#define COS_REV(x) __builtin_amdgcn_cosf(x)
#else
#define SIN_REV(x) __sinf((x) * 6.283185307179586f)
#define COS_REV(x) __cosf((x) * 6.283185307179586f)
#endif

__device__ __forceinline__ float sigmoidf_(float v) { return 1.0f / (1.0f + __expf(-v)); }

__device__ __forceinline__ bf16x8 cvt8(const float* p) {
  const f32x4* p4 = (const f32x4*)p;
  f32x4 lo = p4[0], hi = p4[1];
  bf16x8 r;
#pragma unroll
  for (int j = 0; j < 4; ++j) { r[j] = (bf16)lo[j]; r[j + 4] = (bf16)hi[j]; }
  return r;
}

__device__ __forceinline__ bf16x8 cvt8v(f32x4 lo, f32x4 hi) {
  bf16x8 r;
#pragma unroll
  for (int j = 0; j < 4; ++j) { r[j] = (bf16)lo[j]; r[j + 4] = (bf16)hi[j]; }
  return r;
}

// async global->LDS, 16B per lane; LDS dest = wave-uniform base + lane*16
__device__ __forceinline__ void load_lds16(const bf16* g, bf16* l) {
  __builtin_amdgcn_global_load_lds(
      (const __attribute__((address_space(1))) void*)g,
      (__attribute__((address_space(3))) void*)l, 16, 0, 0);
}

// ---------------- convert weights f32 -> bf16 into wb ------------------------
// layout in wb: [0,196608) ipw | [196608,262144) ow | [262144,458752) w1
__global__ __launch_bounds__(256) void cvtw_ker(const float* __restrict__ ipw,
                                                const float* __restrict__ ow,
                                                const float* __restrict__ w1,
                                                bf16* __restrict__ wb) {
  int e = (blockIdx.x * 256 + threadIdx.x) * 8;
  const float* src; int off;
  if (e < 196608)      { src = ipw; off = e; }
  else if (e < 262144) { src = ow;  off = e - 196608; }
  else                 { src = w1;  off = e - 262144; }
  *(bf16x8*)(wb + e) = cvt8(src + off);
}

// ---------------- weight combine: fold bev_w2 into Wk ------------------------
// kp = kk@wk^T + bk with kk = x_neigh + h@w2^T + b2
//    = x_neigh@wk^T + h@(wk.w2)^T + (wk.b2 + bk)
__global__ __launch_bounds__(256) void wcomb_ker(const float* __restrict__ ipw,
                                                 const float* __restrict__ ipb,
                                                 const float* __restrict__ w2f,
                                                 const float* __restrict__ b2f,
                                                 bf16* __restrict__ Wc,
                                                 float* __restrict__ bkf) {
  __shared__ float row[256];
  __shared__ float red[256];
  const int j = blockIdx.x, l = threadIdx.x;
  row[l] = ipw[65536 + j * 256 + l];  // wk row j (ipw rows [256,512))
  __syncthreads();
  float acc = 0.f;
#pragma unroll 4
  for (int m = 0; m < 256; ++m) acc += row[m] * w2f[m * 256 + l];
  Wc[(size_t)j * 512 + l] = (bf16)acc;
  Wc[(size_t)j * 512 + 256 + l] = (bf16)row[l];
  red[l] = row[l] * b2f[l];
  __syncthreads();
  for (int s = 128; s > 0; s >>= 1) {
    if (l < s) red[l] += red[l + s];
    __syncthreads();
  }
  if (l == 0) bkf[j] = ipb[256 + j] + red[0];
}

// ---------------- tall GEMM core ---------------------------------------------
// C[M x 256] = EPI( A[M x K] @ W[256 x K]^T + bias )
// Tile 256(M) x 64(N), BK=64, 4 waves stacked over M (64 rows each, acc[4][4]).
// Tall tile halves B-traffic vs 128x128 (traffic = M*N*K*2/Mtile).
// Full double-buffer (As[2]+Bs[2], 80 KB), ONE barrier per K-step:
//   stage(t+1 -> buf p^1) || compute(buf p) ; barrier ; flip.
// A: global->reg fetch EARLY, cvt+ds_write LATE (T14 split hides latency).
// B: global_load_lds DMA with pre-swizzled SOURCE; reads XOR-swizzled.
// XOR swizzle (16B slot s of row r holds k-slot s^(r&7)) -> conflict-free b128.
// AMODE: 0=bf16 ws A | 1=generate sine-embed pe | 2=x neigh rows (f32)
//        3=x ego rows (f32) | 4=f32 ws rows | 5=concat [h bf16 | x f32] (K=512)
// EPI:   0=relu->bf16 | 2=bf16 | 3=4*(x_ego+v)->f32 | 4=4*(egoPrev+v)->f32
// COPYX (AMODE2): store fetched x rows to outF (fuses the out=x passthrough).
template <int AMODE, int EPI, int KDIM, bool COPYX>
__global__ __launch_bounds__(256, 2) void gemm_ker(
    const bf16* __restrict__ A, const float* __restrict__ Af,
    const bf16* __restrict__ W, const float* __restrict__ bias,
    const float* __restrict__ x, const float* __restrict__ rp,
    const float* __restrict__ pm, const float* __restrict__ egoPrev,
    bf16* __restrict__ outB, float* __restrict__ outF) {
  __shared__ bf16 As[2][256][64];  // 64 KB
  __shared__ bf16 Bs[2][64][64];   // 16 KB

  constexpr int NS = KDIM / 64;

  const int tid = threadIdx.x;
  const int bidm = blockIdx.x >> 2;
  const int bidn = blockIdx.x & 3;
  const int rowBase = bidm << 8;
  const int colBase = bidn << 6;

  const int wave = tid >> 6, lane = tid & 63;
  const int m16 = lane & 15, quad = lane >> 4;
  const int sA = m16 & 7;   // read-side swizzle key (row&7 == m16&7)
  const int sT = tid & 7;   // write-side swizzle key (A row = tid)

  const int rgA = rowBase + tid;  // the A row this thread stages

  const float* afp = nullptr;
  float tr0 = 0.f, tr1 = 0.f, tr2 = 0.f;
  if constexpr (AMODE == 1) {
    int b = rgA >> 13, j = (rgA >> 11) & 3, q = rgA & 2047;
    int t = b * 5 + 1 + j;
    const float* rpp = rp + ((size_t)t * QN + q) * 3;
    float r0 = rpp[0] * 281.6f - 140.8f;
    float r1 = rpp[1] * 80.0f - 40.0f;
    float r2 = rpp[2] * 4.0f - 3.0f;
    const float* T = pm + (size_t)t * 80;
    tr0 = sigmoidf_(T[0] * r0 + T[1] * r1 + T[2] * r2 + T[3]);
    tr1 = sigmoidf_(T[4] * r0 + T[5] * r1 + T[6] * r2 + T[7]);
    tr2 = sigmoidf_(T[8] * r0 + T[9] * r1 + T[10] * r2 + T[11]);
  } else if constexpr (AMODE == 2 || AMODE == 5) {
    int b = rgA >> 13, j = (rgA >> 11) & 3, q = rgA & 2047;
    afp = x + (((size_t)q * 40 + b * 5 + 1 + j) << 8);
  } else if constexpr (AMODE == 3) {
    int b = rgA >> 11, q = rgA & 2047;
    afp = x + (((size_t)q * 40 + b * 5) << 8);
  } else if constexpr (AMODE == 4) {
    afp = Af + (size_t)rgA * 256;
  }
  float* dstX = nullptr;
  if constexpr (COPYX) dstX = outF + (afp - x);

  // B DMA: 2 instrs/thread/step; instr i covers Bs rows [wave*8+32i, +8).
  // Source k-slot pre-swizzled: (lane&7) ^ (lane>>3) (row&7 == lane>>3).
#define STAGE_B(PP, KO)                                                       \
  {                                                                           \
    _Pragma("unroll") for (int i_ = 0; i_ < 2; ++i_) {                        \
      int rg_ = (wave << 3) + (i_ << 5) + (lane >> 3);                        \
      const bf16* src_ = W + (size_t)(colBase + rg_) * KDIM + (KO) +          \
                         (((lane & 7) ^ (lane >> 3)) << 3);                   \
      load_lds16(src_, &Bs[(PP)][(wave << 3) + (i_ << 5)][0]);                \
    }                                                                         \
  }

#define FETCH_A(KO)                                                           \
  if constexpr (AMODE == 0) {                                                 \
    _Pragma("unroll") for (int j_ = 0; j_ < 8; ++j_)                          \
        aB[j_] = ((const bf16x8*)(A + (size_t)rgA * KDIM + (KO)))[j_];        \
  } else if constexpr (AMODE == 5) {                                          \
    if ((KO) < 256) {                                                         \
      _Pragma("unroll") for (int j_ = 0; j_ < 8; ++j_)                        \
          aB[j_] = ((const bf16x8*)(A + ((size_t)rgA << 8) + (KO)))[j_];      \
    } else {                                                                  \
      _Pragma("unroll") for (int j_ = 0; j_ < 16; ++j_)                       \
          aF[j_] = ((const f32x4*)(afp + (KO) - 256))[j_];                    \
    }                                                                         \
  } else if constexpr (AMODE != 1) {                                          \
    _Pragma("unroll") for (int j_ = 0; j_ < 16; ++j_)                         \
        aF[j_] = ((const f32x4*)(afp + (KO)))[j_];                            \
  }

#define FINISH_A(PP, KO)                                                      \
  {                                                                           \
    bf16x8 v_[8];                                                             \
    if constexpr (AMODE == 1) {                                               \
      const int c_ = (KO) >> 8;                                               \
      const float tc_ = (c_ == 0) ? tr0 : (c_ == 1 ? tr1 : tr2);              \
      float fr_ = exp2f((float)(((KO) & 255) >> 1) * -0.10381025296522975f);  \
      _Pragma("unroll") for (int js_ = 0; js_ < 32; ++js_) {                  \
        float a_ = tc_ * fr_;                                                 \
        v_[js_ >> 2][(js_ & 3) * 2] = (bf16)SIN_REV(a_);                      \
        v_[js_ >> 2][(js_ & 3) * 2 + 1] = (bf16)COS_REV(a_);                  \
        fr_ *= 0.9305720409296979f;                                           \
      }                                                                       \
    } else if constexpr (AMODE == 0) {                                        \
      _Pragma("unroll") for (int j_ = 0; j_ < 8; ++j_) v_[j_] = aB[j_];       \
    } else if constexpr (AMODE == 5) {                                        \
      if ((KO) < 256) {                                                       \
        _Pragma("unroll") for (int j_ = 0; j_ < 8; ++j_) v_[j_] = aB[j_];     \
      } else {                                                                \
        _Pragma("unroll") for (int j_ = 0; j_ < 8; ++j_)                      \
            v_[j_] = cvt8v(aF[2 * j_], aF[2 * j_ + 1]);                       \
      }                                                                       \
    } else {                                                                  \
      _Pragma("unroll") for (int j_ = 0; j_ < 8; ++j_)                        \
          v_[j_] = cvt8v(aF[2 * j_], aF[2 * j_ + 1]);                         \
      if constexpr (COPYX) {                                                  \
        _Pragma("unroll") for (int j_ = 0; j_ < 16; ++j_)                     \
            ((f32x4*)(dstX + (KO)))[j_] = aF[j_];                             \
      }                                                                       \
    }                                                                         \
    _Pragma("unroll") for (int j_ = 0; j_ < 8; ++j_)                          \
        *(bf16x8*)(&As[(PP)][tid][(j_ ^ sT) << 3]) = v_[j_];                  \
  }

  f32x4 acc[4][4] = {};

  // prologue: stage k=0 into buffer 0
  {
    f32x4 aF[16]; bf16x8 aB[8];
    FETCH_A(0);
    STAGE_B(0, 0);
    FINISH_A(0, 0);
  }
  __syncthreads();

#pragma unroll
  for (int t = 0; t < NS; ++t) {
    const int p = t & 1;
    const int kn = (t + 1) << 6;
    f32x4 aF[16]; bf16x8 aB[8];
    if (t + 1 < NS) {
      FETCH_A(kn);          // issue A-loads early (latency under compute)
      STAGE_B(p ^ 1, kn);   // issue B-DMA early
    }
    // compute on buffer p
#pragma unroll
    for (int kk = 0; kk < 2; ++kk) {
      const int ks = (((kk << 2) + quad) ^ sA) << 3;
      bf16x8 afr[4], bfr[4];
#pragma unroll
      for (int mt = 0; mt < 4; ++mt)
        afr[mt] = *(const bf16x8*)(&As[p][(wave << 6) + (mt << 4) + m16][ks]);
#pragma unroll
      for (int nt = 0; nt < 4; ++nt)
        bfr[nt] = *(const bf16x8*)(&Bs[p][(nt << 4) + m16][ks]);
#pragma unroll
      for (int mt = 0; mt < 4; ++mt)
#pragma unroll
        for (int nt = 0; nt < 4; ++nt)
          acc[mt][nt] = __builtin_amdgcn_mfma_f32_16x16x32_bf16(
              afr[mt], bfr[nt], acc[mt][nt], 0, 0, 0);
    }
    if (t + 1 < NS) FINISH_A(p ^ 1, kn);  // cvt/trig + LDS write (loads done)
    __syncthreads();
  }
#undef STAGE_B
#undef FETCH_A
#undef FINISH_A

  // epilogue: row = quad*4+rg (A side), col = m16 (B side)
#pragma unroll
  for (int mt = 0; mt < 4; ++mt) {
#pragma unroll
    for (int nt = 0; nt < 4; ++nt) {
      const int col = colBase + (nt << 4) + m16;
      const float bv = bias[col];
#pragma unroll
      for (int rg = 0; rg < 4; ++rg) {
        const int r = rowBase + (wave << 6) + (mt << 4) + (quad << 2) + rg;
        float v = acc[mt][nt][rg] + bv;
        if constexpr (EPI == 0) {
          outB[(size_t)r * 256 + col] = (bf16)fmaxf(v, 0.0f);
        } else if constexpr (EPI == 2) {
          outB[(size_t)r * 256 + col] = (bf16)v;
        } else if constexpr (EPI == 3) {
          int b = r >> 11, q = r & 2047;
          float xe = x[(((size_t)q * 40 + b * 5) << 8) + col];
          outF[(size_t)r * 256 + col] = 4.0f * (xe + v);
        } else if constexpr (EPI == 4) {
          int b = r >> 11, q = r & 2047;
          float e1 = egoPrev[(size_t)r * 256 + col];
          outF[(((size_t)q * 40 + b * 5) << 8) + col] = 4.0f * (e1 + v);
        }
      }
    }
  }
}

// ---------------- attention: 4-way softmax per (q-row, head) -----------------
__global__ __launch_bounds__(256) void attn_ker(const bf16* __restrict__ qp,
                                                const bf16* __restrict__ kp,
                                                const bf16* __restrict__ vp,
                                                bf16* __restrict__ o) {
  int p = blockIdx.x * 256 + threadIdx.x;  // 16384 rows * 8 heads
  int h = p & 7;
  int re = p >> 3;
  int b = re >> 11;
  int q = re & 2047;
  const bf16x8* qpv = (const bf16x8*)(qp + ((size_t)re << 8) + h * 32);
  float qv[32];
#pragma unroll
  for (int i = 0; i < 4; ++i) {
    bf16x8 t = qpv[i];
#pragma unroll
    for (int j = 0; j < 8; ++j) qv[i * 8 + j] = (float)t[j];
  }
  size_t base = ((size_t)(b * 4) * QN + q) * 256 + h * 32;
  float s[4];
#pragma unroll
  for (int m = 0; m < 4; ++m) {
    const bf16x8* kv = (const bf16x8*)(kp + base + (size_t)m * (QN * 256));
    float a = 0.f;
#pragma unroll
    for (int i = 0; i < 4; ++i) {
      bf16x8 t = kv[i];
#pragma unroll
      for (int j = 0; j < 8; ++j) a += qv[i * 8 + j] * (float)t[j];
    }
    s[m] = a * 0.17677669529663687f;  // 1/sqrt(32)
  }
  float mx = fmaxf(fmaxf(s[0], s[1]), fmaxf(s[2], s[3]));
  float e0 = __expf(s[0] - mx), e1 = __expf(s[1] - mx);
  float e2 = __expf(s[2] - mx), e3 = __expf(s[3] - mx);
  float inv = 1.0f / (e0 + e1 + e2 + e3);
  float w[4] = {e0 * inv, e1 * inv, e2 * inv, e3 * inv};
  float ov[32] = {};
#pragma unroll
  for (int m = 0; m < 4; ++m) {
    const bf16x8* vv = (const bf16x8*)(vp + base + (size_t)m * (QN * 256));
#pragma unroll
    for (int i = 0; i < 4; ++i) {
      bf16x8 t = vv[i];
#pragma unroll
      for (int j = 0; j < 8; ++j) ov[i * 8 + j] += w[m] * (float)t[j];
    }
  }
  bf16x8* op = (bf16x8*)(o + ((size_t)re << 8) + h * 32);
#pragma unroll
  for (int i = 0; i < 4; ++i) {
    bf16x8 t;
#pragma unroll
    for (int j = 0; j < 8; ++j) t[j] = (bf16)ov[i * 8 + j];
    op[i] = t;
  }
}

extern "C" void kernel_launch(void* const* d_in, const int* in_sizes, int n_in,
                              void* d_out, int out_size, void* d_ws, size_t ws_size,
                              hipStream_t stream) {
  (void)n_in; (void)out_size; (void)ws_size;
  const float* x   = (const float*)d_in[0];   // (2048, 40, 256)
  const float* rp  = (const float*)d_in[1];   // (40, 2048, 3)
  const float* pm  = (const float*)d_in[2];   // (8, 5, 5, 4, 4)
  const int wbase = (in_sizes[3] == 8) ? 4 : 3;  // record_len probe
  const float* ipw = (const float*)d_in[wbase + 0];  // (768, 256)
  const float* ipb = (const float*)d_in[wbase + 1];  // (768,)
  const float* ow  = (const float*)d_in[wbase + 2];  // (256, 256)
  const float* obv = (const float*)d_in[wbase + 3];  // (256,)
  const float* w1  = (const float*)d_in[wbase + 4];  // (256, 768)
  const float* b1  = (const float*)d_in[wbase + 5];
  const float* w2  = (const float*)d_in[wbase + 6];  // (256, 256)
  const float* b2  = (const float*)d_in[wbase + 7];
  float* out = (float*)d_out;
  char* ws = (char*)d_ws;

  // ws regions:
  bf16* h    = (bf16*)(ws + 0);           // 32Mi, dead after kp GEMM
  bf16* qp   = (bf16*)(ws + 0);           // 8Mi  (over dead h)
  bf16* oo   = (bf16*)(ws + 8388608);     // 8Mi  (over dead h)
  bf16* kp   = (bf16*)(ws + 33554432);    // 32Mi, live to attn2
  bf16* vp   = (bf16*)(ws + 67108864);    // 32Mi, live to attn2
  float* egoF = (float*)(ws + 100663296); // 16Mi, live to final
  bf16* wb   = (bf16*)(ws + 117440512);   // bf16 weights
  bf16* Wc   = (bf16*)(ws + 118489088);   // 256KiB combined [wkk|wk] (256x512)
  float* bkf = (float*)(ws + 118751232);  // 1KiB folded k bias
  const bf16* wq  = wb;
  const bf16* wv  = wb + 131072;
  const bf16* owb = wb + 196608;
  const bf16* w1b = wb + 262144;

  // 1) bf16 weights (ipw + ow + w1 = 458752 elems)
  cvtw_ker<<<224, 256, 0, stream>>>(ipw, ow, w1, wb);
  // 1b) fold bev_w2 into Wk: Wc = [wk@w2 | wk], bkf = bk + wk@b2
  wcomb_ker<<<256, 256, 0, stream>>>(ipw, ipb, w2, b2, Wc, bkf);
  // 2) h = relu(pe @ w1^T + b1)   [tall tile, trig-generated A]
  gemm_ker<1, 0, 768, false><<<1024, 256, 0, stream>>>(
      nullptr, nullptr, w1b, b1, x, rp, pm, nullptr, h, nullptr);
  // 3) kp = x_neigh@wk^T + h@wkk^T + bkf   (K=512 concat GEMM)
  gemm_ker<5, 2, 512, false><<<1024, 256, 0, stream>>>(
      h, nullptr, Wc, bkf, x, rp, pm, nullptr, kp, nullptr);
  // 4) vp = x_neigh @ Wv^T + bv; ALSO copies x neighbor rows -> out (COPYX)
  gemm_ker<2, 2, 256, true><<<1024, 256, 0, stream>>>(
      nullptr, nullptr, wv, ipb + 512, x, rp, pm, nullptr, vp, out);
  // --- iteration 1 ---
  gemm_ker<3, 2, 256, false><<<256, 256, 0, stream>>>(
      nullptr, nullptr, wq, ipb, x, rp, pm, nullptr, qp, nullptr);
  attn_ker<<<512, 256, 0, stream>>>(qp, kp, vp, oo);
  gemm_ker<0, 3, 256, false><<<256, 256, 0, stream>>>(
      oo, nullptr, owb, obv, x, rp, pm, nullptr, nullptr, egoF);
  // --- iteration 2 ---
  gemm_ker<4, 2, 256, false><<<256, 256, 0, stream>>>(
      nullptr, egoF, wq, ipb, x, rp, pm, nullptr, qp, nullptr);
  attn_ker<<<512, 256, 0, stream>>>(qp, kp, vp, oo);
  gemm_ker<0, 4, 256, false><<<256, 256, 0, stream>>>(
      oo, nullptr, owb, obv, x, rp, pm, egoF, nullptr, out);
}

// Round 5
// 369.077 us; speedup vs baseline: 1.4083x; 1.4083x over previous
//
#include <hip/hip_runtime.h>
#include <cstdint>
#include <cstddef>

typedef __bf16 bf16;
typedef __attribute__((ext_vector_type(8))) __bf16 bf16x8;
typedef __attribute__((ext_vector_type(4))) float f32x4;
typedef __attribute__((ext_vector_type(4))) unsigned int u32x4;

#define QN 2048

#if __has_builtin(__builtin_amdgcn_sinf)
#define SIN_REV(x) __builtin_amdgcn_sinf(x)
#define COS_REV(x) __builtin_amdgcn_cosf(x)
#else
#define SIN_REV(x) __sinf((x) * 6.283185307179586f)
#define COS_REV(x) __cosf((x) * 6.283185307179586f)
#endif

__device__ __forceinline__ float sigmoidf_(float v) { return 1.0f / (1.0f + __expf(-v)); }

__device__ __forceinline__ bf16x8 cvt8(const float* p) {
  const f32x4* p4 = (const f32x4*)p;
  f32x4 lo = p4[0], hi = p4[1];
  bf16x8 r;
#pragma unroll
  for (int j = 0; j < 4; ++j) { r[j] = (bf16)lo[j]; r[j + 4] = (bf16)hi[j]; }
  return r;
}

// async global->LDS, 16B per lane; LDS dest = wave-uniform base + lane*16
__device__ __forceinline__ void load_lds16(const bf16* g, bf16* l) {
  __builtin_amdgcn_global_load_lds(
      (const __attribute__((address_space(1))) void*)g,
      (__attribute__((address_space(3))) void*)l, 16, 0, 0);
}

// ---------------- copy: out = x (neighbor rows passthrough) ------------------
// Ego rows (t%5==0) skipped: fused iter kernel writes every ego row of out.
__global__ __launch_bounds__(256) void copy_ker(const u32x4* __restrict__ in,
                                                u32x4* __restrict__ out, int n) {
  int i = blockIdx.x * 256 + threadIdx.x;
  if (i >= n) return;
  int t = (i >> 6) % 40;
  if ((t % 5) == 0) return;
  out[i] = in[i];
}

// ---------------- convert weights f32 -> bf16 into wb ------------------------
// layout in wb: [0,196608) ipw | [196608,262144) ow | [262144,458752) w1
__global__ __launch_bounds__(256) void cvtw_ker(const float* __restrict__ ipw,
                                                const float* __restrict__ ow,
                                                const float* __restrict__ w1,
                                                bf16* __restrict__ wb) {
  int e = (blockIdx.x * 256 + threadIdx.x) * 8;
  const float* src; int off;
  if (e < 196608)      { src = ipw; off = e; }
  else if (e < 262144) { src = ow;  off = e - 196608; }
  else                 { src = w1;  off = e - 262144; }
  *(bf16x8*)(wb + e) = cvt8(src + off);
}

// ---------------- weight combine: fold bev_w2 into Wk ------------------------
// kp = kk@wk^T + bk with kk = x_neigh + h@w2^T + b2
//    = x_neigh@wk^T + h@(wk.w2)^T + (wk.b2 + bk)
__global__ __launch_bounds__(256) void wcomb_ker(const float* __restrict__ ipw,
                                                 const float* __restrict__ ipb,
                                                 const float* __restrict__ w2f,
                                                 const float* __restrict__ b2f,
                                                 bf16* __restrict__ Wc,
                                                 float* __restrict__ bkf) {
  __shared__ float row[256];
  __shared__ float red[256];
  const int j = blockIdx.x, l = threadIdx.x;
  row[l] = ipw[65536 + j * 256 + l];  // wk row j (ipw rows [256,512))
  __syncthreads();
  float acc = 0.f;
#pragma unroll 4
  for (int m = 0; m < 256; ++m) acc += row[m] * w2f[m * 256 + l];
  Wc[(size_t)j * 512 + l] = (bf16)acc;
  Wc[(size_t)j * 512 + 256 + l] = (bf16)row[l];
  red[l] = row[l] * b2f[l];
  __syncthreads();
  for (int s = 128; s > 0; s >>= 1) {
    if (l < s) red[l] += red[l + s];
    __syncthreads();
  }
  if (l == 0) bkf[j] = ipb[256 + j] + red[0];
}

// ---------------- GEMM core (m97-style, exact round-1 version) ---------------
// C[M x 256] = EPI( A[M x K] @ W[256 x K]^T + bias )
// AMODE: 0=bf16 ws A | 1=generate sine-embed pe (K=768) | 2=x neigh rows (f32)
//        5=concat [h bf16 | x_neigh f32] (K=512)
// EPI:   0=relu->bf16 | 2=bf16
template <int AMODE, int EPI, int KDIM>
__global__ __launch_bounds__(256) void gemm_ker(
    const bf16* __restrict__ A, const bf16* __restrict__ W,
    const float* __restrict__ bias, const float* __restrict__ x,
    const float* __restrict__ rp, const float* __restrict__ pm,
    bf16* __restrict__ outB) {
  __shared__ bf16 As[128][40];  // +8 pad: 80 B stride
  __shared__ bf16 Bs[128][32];  // unpadded: global_load_lds order

  const int tid = threadIdx.x;
  const int bidm = blockIdx.x >> 1;
  const int bidn = blockIdx.x & 1;
  const int rowBase = bidm << 7;
  const int colBase = bidn << 7;

  const int wave = tid >> 6, lane = tid & 63;
  const int m16 = lane & 15, quad = lane >> 4;
  const int wr = wave >> 1, wc = wave & 1;

  const int sRow = tid >> 1, sHalf = tid & 1;
  const int rgA = rowBase + sRow;

  const float* afp = nullptr;
  float tr0 = 0.f, tr1 = 0.f, tr2 = 0.f;
  if constexpr (AMODE == 1) {
    int b = rgA >> 13, j = (rgA >> 11) & 3, q = rgA & 2047;
    int t = b * 5 + 1 + j;
    const float* rpp = rp + ((size_t)t * QN + q) * 3;
    float r0 = rpp[0] * 281.6f - 140.8f;
    float r1 = rpp[1] * 80.0f - 40.0f;
    float r2 = rpp[2] * 4.0f - 3.0f;
    const float* T = pm + (size_t)t * 80;
    tr0 = sigmoidf_(T[0] * r0 + T[1] * r1 + T[2] * r2 + T[3]);
    tr1 = sigmoidf_(T[4] * r0 + T[5] * r1 + T[6] * r2 + T[7]);
    tr2 = sigmoidf_(T[8] * r0 + T[9] * r1 + T[10] * r2 + T[11]);
  } else if constexpr (AMODE == 2 || AMODE == 5) {
    int b = rgA >> 13, j = (rgA >> 11) & 3, q = rgA & 2047;
    afp = x + (((size_t)q * 40 + b * 5 + 1 + j) << 8);
  }

  const bf16* wsrc = W + (size_t)(colBase + (wave << 5) + (lane >> 2)) * KDIM + ((lane & 3) << 3);
  bf16* bdst0 = &Bs[(wave << 5)][0];
  bf16* bdst1 = &Bs[(wave << 5) + 16][0];

  f32x4 acc[4][4] = {};

  for (int k0 = 0; k0 < KDIM; k0 += 32) {
    load_lds16(wsrc + k0, bdst0);
    load_lds16(wsrc + (size_t)16 * KDIM + k0, bdst1);

    bf16x8 a0, a1;
    if constexpr (AMODE == 1) {
      int c = k0 >> 8;
      float tc = (c == 0) ? tr0 : (c == 1 ? tr1 : tr2);
      int ti0 = ((k0 & 255) + (sHalf << 4)) >> 1;
      float freq = exp2f((float)ti0 * -0.10381025296522975f);
#pragma unroll
      for (int p = 0; p < 4; ++p) {
        float ang = tc * freq;
        a0[2 * p]     = (bf16)SIN_REV(ang);
        a0[2 * p + 1] = (bf16)COS_REV(ang);
        freq *= 0.93057204092467f;
      }
#pragma unroll
      for (int p = 0; p < 4; ++p) {
        float ang = tc * freq;
        a1[2 * p]     = (bf16)SIN_REV(ang);
        a1[2 * p + 1] = (bf16)COS_REV(ang);
        freq *= 0.93057204092467f;
      }
    } else if constexpr (AMODE == 0) {
      const bf16* ap = A + (size_t)rgA * KDIM + k0 + (sHalf << 4);
      a0 = ((const bf16x8*)ap)[0];
      a1 = ((const bf16x8*)ap)[1];
    } else if constexpr (AMODE == 5) {
      if (k0 < 256) {
        const bf16* ap = A + ((size_t)rgA << 8) + k0 + (sHalf << 4);
        a0 = ((const bf16x8*)ap)[0];
        a1 = ((const bf16x8*)ap)[1];
      } else {
        const float* fp = afp + (k0 - 256) + (sHalf << 4);
        a0 = cvt8(fp);
        a1 = cvt8(fp + 8);
      }
    } else {
      const float* fp = afp + k0 + (sHalf << 4);
      a0 = cvt8(fp);
      a1 = cvt8(fp + 8);
    }
    *(bf16x8*)(&As[sRow][sHalf << 4]) = a0;
    *(bf16x8*)(&As[sRow][(sHalf << 4) + 8]) = a1;
    __syncthreads();  // drains vmcnt (DMA) + lgkmcnt (ds_write)

    bf16x8 afr[4], bfr[4];
#pragma unroll
    for (int mt = 0; mt < 4; ++mt)
      afr[mt] = *(const bf16x8*)(&As[(wr << 6) + (mt << 4) + m16][quad << 3]);
#pragma unroll
    for (int nt = 0; nt < 4; ++nt)
      bfr[nt] = *(const bf16x8*)(&Bs[(wc << 6) + (nt << 4) + m16][quad << 3]);
#pragma unroll
    for (int mt = 0; mt < 4; ++mt)
#pragma unroll
      for (int nt = 0; nt < 4; ++nt)
        acc[mt][nt] = __builtin_amdgcn_mfma_f32_16x16x32_bf16(
            afr[mt], bfr[nt], acc[mt][nt], 0, 0, 0);
    __syncthreads();
  }

#pragma unroll
  for (int mt = 0; mt < 4; ++mt) {
#pragma unroll
    for (int nt = 0; nt < 4; ++nt) {
      const int col = colBase + (wc << 6) + (nt << 4) + m16;
      const float bv = bias[col];
#pragma unroll
      for (int rg = 0; rg < 4; ++rg) {
        const int r = rowBase + (wr << 6) + (mt << 4) + (quad << 2) + rg;
        float v = acc[mt][nt][rg] + bv;
        if constexpr (EPI == 0) {
          outB[(size_t)r * 256 + col] = (bf16)fmaxf(v, 0.0f);
        } else {
          outB[(size_t)r * 256 + col] = (bf16)v;
        }
      }
    }
  }
}

// ---------------- fused iteration kernel -------------------------------------
// Per block: 32 q-rows; whole 2-iteration recurrence in one kernel.
//   iter: qp = ego@Wq^T+bq (MFMA, LDS out) -> attn (in-place LDS) ->
//         o-proj (MFMA) -> ego1 = 4*(ego_in + o) kept in REGISTERS + LDS bf16.
// LDS: P1 (ego, 16K) + P2 (qp/oo, 16K) + Bs (W k-slice, 16K) = 48 KB -> 3/CU.
// P1/P2 use XOR 16B-slot swizzle (slot ^ (row&7)) -> conflict-free b128 reads.
// Attn in-place: each thread writes exactly the P2 slice it read.
__device__ __forceinline__ void proj32(const bf16 (*AP)[256], bf16 (*BsP)[32],
                                       const bf16* __restrict__ WB,
                                       f32x4 (*acc)[4], int wave, int lane) {
  const int m16 = lane & 15, quad = lane >> 4;
  for (int k0 = 0; k0 < 256; k0 += 32) {
#pragma unroll
    for (int i = 0; i < 4; ++i) {
      const bf16* src = WB +
          (size_t)((wave << 6) + (i << 4) + (lane >> 2)) * 256 + k0 +
          ((lane & 3) << 3);
      load_lds16(src, &BsP[(wave << 6) + (i << 4)][0]);
    }
    __syncthreads();  // DMA drained; also orders prior LDS writes vs reads
    bf16x8 afr[2], bfr[4];
#pragma unroll
    for (int mt = 0; mt < 2; ++mt) {
      const int r = (mt << 4) + m16;
      afr[mt] = *(const bf16x8*)(&AP[r][(((k0 >> 3) + quad) ^ (r & 7)) << 3]);
    }
#pragma unroll
    for (int nt = 0; nt < 4; ++nt)
      bfr[nt] = *(const bf16x8*)(&BsP[(wave << 6) + (nt << 4) + m16][quad << 3]);
#pragma unroll
    for (int mt = 0; mt < 2; ++mt)
#pragma unroll
      for (int nt = 0; nt < 4; ++nt)
        acc[mt][nt] = __builtin_amdgcn_mfma_f32_16x16x32_bf16(
            afr[mt], bfr[nt], acc[mt][nt], 0, 0, 0);
    __syncthreads();
  }
}

__device__ __forceinline__ void attn_phase(bf16 (*P)[256],
                                           const bf16* __restrict__ kp,
                                           const bf16* __restrict__ vp,
                                           int rowBase, int tid) {
  const int r = tid >> 3, h = tid & 7;
  const int re = rowBase + r, b = re >> 11, q = re & 2047;
  float qv[32];
#pragma unroll
  for (int i = 0; i < 4; ++i) {
    bf16x8 t = *(const bf16x8*)(&P[r][((((h << 2) + i)) ^ (r & 7)) << 3]);
#pragma unroll
    for (int j = 0; j < 8; ++j) qv[i * 8 + j] = (float)t[j];
  }
  const size_t base = ((size_t)(b * 4) * QN + q) * 256 + h * 32;
  float s[4];
#pragma unroll
  for (int m = 0; m < 4; ++m) {
    const bf16x8* kv = (const bf16x8*)(kp + base + (size_t)m * (QN * 256));
    float a = 0.f;
#pragma unroll
    for (int i = 0; i < 4; ++i) {
      bf16x8 t = kv[i];
#pragma unroll
      for (int j = 0; j < 8; ++j) a += qv[i * 8 + j] * (float)t[j];
    }
    s[m] = a * 0.17677669529663687f;  // 1/sqrt(32)
  }
  float mx = fmaxf(fmaxf(s[0], s[1]), fmaxf(s[2], s[3]));
  float e0 = __expf(s[0] - mx), e1 = __expf(s[1] - mx);
  float e2 = __expf(s[2] - mx), e3 = __expf(s[3] - mx);
  float inv = 1.0f / (e0 + e1 + e2 + e3);
  float w[4] = {e0 * inv, e1 * inv, e2 * inv, e3 * inv};
  float ov[32] = {};
#pragma unroll
  for (int m = 0; m < 4; ++m) {
    const bf16x8* vv = (const bf16x8*)(vp + base + (size_t)m * (QN * 256));
#pragma unroll
    for (int i = 0; i < 4; ++i) {
      bf16x8 t = vv[i];
#pragma unroll
      for (int j = 0; j < 8; ++j) ov[i * 8 + j] += w[m] * (float)t[j];
    }
  }
#pragma unroll
  for (int i = 0; i < 4; ++i) {
    bf16x8 t;
#pragma unroll
    for (int j = 0; j < 8; ++j) t[j] = (bf16)ov[i * 8 + j];
    *(bf16x8*)(&P[r][((((h << 2) + i)) ^ (r & 7)) << 3]) = t;
  }
}

__global__ __launch_bounds__(256, 2) void iter_ker(
    const bf16* __restrict__ kp, const bf16* __restrict__ vp,
    const bf16* __restrict__ wq, const bf16* __restrict__ owb,
    const float* __restrict__ qb, const float* __restrict__ ob,
    const float* __restrict__ x, float* __restrict__ out) {
  __shared__ bf16 P1[32][256];
  __shared__ bf16 P2[32][256];
  __shared__ bf16 Bs[256][32];

  const int tid = threadIdx.x;
  const int rowBase = blockIdx.x << 5;
  const int wave = tid >> 6, lane = tid & 63;
  const int m16 = lane & 15, quad = lane >> 4;

  // stage ego0 = bf16(x_ego) into P1 (swizzled)
  {
    const int r = tid >> 3, e = tid & 7;
    const int re = rowBase + r, b = re >> 11, q = re & 2047;
    const float* src = x + (((size_t)q * 40 + b * 5) << 8) + (e << 5);
#pragma unroll
    for (int s = 0; s < 4; ++s) {
      bf16x8 v = cvt8(src + s * 8);
      *(bf16x8*)(&P1[r][((((e << 2) + s)) ^ (r & 7)) << 3]) = v;
    }
  }

  float e1r[2][4][4];
  f32x4 acc[2][4];

#define ZACC                                                                  \
  { _Pragma("unroll") for (int mt = 0; mt < 2; ++mt)                          \
    _Pragma("unroll") for (int nt = 0; nt < 4; ++nt) {                        \
      f32x4 z = {0.f, 0.f, 0.f, 0.f}; acc[mt][nt] = z; } }

#define QEPI                                                                  \
  { _Pragma("unroll") for (int mt = 0; mt < 2; ++mt)                          \
    _Pragma("unroll") for (int nt = 0; nt < 4; ++nt) {                        \
      const int col = (wave << 6) + (nt << 4) + m16;                          \
      const float bv = qb[col];                                               \
      _Pragma("unroll") for (int rg = 0; rg < 4; ++rg) {                      \
        const int row = (mt << 4) + (quad << 2) + rg;                         \
        P2[row][(((col >> 3) ^ (row & 7)) << 3) + (col & 7)] =                \
            (bf16)(acc[mt][nt][rg] + bv);                                     \
      } } }

  // ---- iteration 1 ----
  ZACC;
  proj32(P1, Bs, wq, acc, wave, lane);   // qp -> acc
  QEPI;                                   // qp -> P2
  __syncthreads();
  attn_phase(P2, kp, vp, rowBase, tid);   // P2: qp -> oo (in place)
  ZACC;
  proj32(P2, Bs, owb, acc, wave, lane);  // o-proj
  // o-epi: ego1 = 4*(x_ego + o) -> regs + P1(bf16)
#pragma unroll
  for (int mt = 0; mt < 2; ++mt)
#pragma unroll
    for (int nt = 0; nt < 4; ++nt) {
      const int col = (wave << 6) + (nt << 4) + m16;
      const float bv = ob[col];
#pragma unroll
      for (int rg = 0; rg < 4; ++rg) {
        const int row = (mt << 4) + (quad << 2) + rg;
        const int re = rowBase + row, b = re >> 11, q = re & 2047;
        float xe = x[(((size_t)q * 40 + b * 5) << 8) + col];
        float e1 = 4.0f * (xe + acc[mt][nt][rg] + bv);
        e1r[mt][nt][rg] = e1;
        P1[row][(((col >> 3) ^ (row & 7)) << 3) + (col & 7)] = (bf16)e1;
      }
    }

  // ---- iteration 2 ----
  ZACC;
  proj32(P1, Bs, wq, acc, wave, lane);   // internal sync orders P1 writes
  QEPI;
  __syncthreads();
  attn_phase(P2, kp, vp, rowBase, tid);
  ZACC;
  proj32(P2, Bs, owb, acc, wave, lane);
  // final epi: out(ego rows) = 4*(ego1 + o)
#pragma unroll
  for (int mt = 0; mt < 2; ++mt)
#pragma unroll
    for (int nt = 0; nt < 4; ++nt) {
      const int col = (wave << 6) + (nt << 4) + m16;
      const float bv = ob[col];
#pragma unroll
      for (int rg = 0; rg < 4; ++rg) {
        const int row = (mt << 4) + (quad << 2) + rg;
        const int re = rowBase + row, b = re >> 11, q = re & 2047;
        out[(((size_t)q * 40 + b * 5) << 8) + col] =
            4.0f * (e1r[mt][nt][rg] + acc[mt][nt][rg] + bv);
      }
    }
#undef ZACC
#undef QEPI
}

extern "C" void kernel_launch(void* const* d_in, const int* in_sizes, int n_in,
                              void* d_out, int out_size, void* d_ws, size_t ws_size,
                              hipStream_t stream) {
  (void)n_in; (void)out_size; (void)ws_size;
  const float* x   = (const float*)d_in[0];   // (2048, 40, 256)
  const float* rp  = (const float*)d_in[1];   // (40, 2048, 3)
  const float* pm  = (const float*)d_in[2];   // (8, 5, 5, 4, 4)
  const int wbase = (in_sizes[3] == 8) ? 4 : 3;  // record_len probe
  const float* ipw = (const float*)d_in[wbase + 0];  // (768, 256)
  const float* ipb = (const float*)d_in[wbase + 1];  // (768,)
  const float* ow  = (const float*)d_in[wbase + 2];  // (256, 256)
  const float* obv = (const float*)d_in[wbase + 3];  // (256,)
  const float* w1  = (const float*)d_in[wbase + 4];  // (256, 768)
  const float* b1  = (const float*)d_in[wbase + 5];
  const float* w2  = (const float*)d_in[wbase + 6];  // (256, 256)
  const float* b2  = (const float*)d_in[wbase + 7];
  float* out = (float*)d_out;
  char* ws = (char*)d_ws;

  // ws regions:
  bf16* h    = (bf16*)(ws + 0);           // 32Mi, dead after kp GEMM
  bf16* kp   = (bf16*)(ws + 33554432);    // 32Mi, live to iter_ker
  bf16* vp   = (bf16*)(ws + 67108864);    // 32Mi, live to iter_ker
  bf16* wb   = (bf16*)(ws + 100663296);   // bf16 weights
  bf16* Wc   = (bf16*)(ws + 101711872);   // 256KiB combined [wkk|wk] (256x512)
  float* bkf = (float*)(ws + 101974016);  // 1KiB folded k bias
  const bf16* wq  = wb;
  const bf16* wv  = wb + 131072;
  const bf16* owb = wb + 196608;
  const bf16* w1b = wb + 262144;

  // 1) bf16 weights (ipw + ow + w1 = 458752 elems)
  cvtw_ker<<<224, 256, 0, stream>>>(ipw, ow, w1, wb);
  // 1b) fold bev_w2 into Wk: Wc = [wk@w2 | wk], bkf = bk + wk@b2
  wcomb_ker<<<256, 256, 0, stream>>>(ipw, ipb, w2, b2, Wc, bkf);
  // 2) out = x for neighbor rows (ego rows written by iter_ker)
  copy_ker<<<20480, 256, 0, stream>>>((const u32x4*)x, (u32x4*)out, 5242880);
  // 3) h = relu(pe @ w1^T + b1)   [pe generated on the fly]
  gemm_ker<1, 0, 768><<<1024, 256, 0, stream>>>(nullptr, w1b, b1, x, rp, pm, h);
  // 4) kp = x_neigh@wk^T + h@wkk^T + bkf   (K=512 concat GEMM)
  gemm_ker<5, 2, 512><<<1024, 256, 0, stream>>>(h, Wc, bkf, x, rp, pm, kp);
  // 5) vp = x_neigh @ Wv^T + bv
  gemm_ker<2, 2, 256><<<1024, 256, 0, stream>>>(nullptr, wv, ipb + 512, x, rp, pm, vp);
  // 6) fused: both iterations (q-proj + attn + o-proj + ego update)
  iter_ker<<<512, 256, 0, stream>>>(kp, vp, wq, owb, ipb, obv, x, out);
}